// Round 11
// baseline (245.496 us; speedup 1.0000x reference)
//
#include <hip/hip_runtime.h>
#include <hip/hip_fp16.h>
#include <math.h>

#define NSTEPS 256
#define GRIDN  160
#define NVOX   (160 * 160 * 160)
#define NTPA   20                  // tiles per axis (8^3-voxel tiles)
#define NTILES (NTPA * NTPA * NTPA)
#define NREP   8                   // hist replicas (~per-XCD)
#define CAP_R  256                 // item slots per (tile, replica); ~4x hottest
#define ITEM_CAP (4 * 1024 * 1024)

#define INV_SIGMA 0.05233333f      // 2.355/45, fast path (weight only)

struct LorT { float4 a; float4 b; };   // a: p0.xyz, tof ; b: d.xyz, L

// ---- strict voxel path (contract OFF: bit-match f32 numpy floor decisions)
//      + fast validity e (weight tolerance is huge; predicate shared by all users)
__device__ __forceinline__ bool sample_vox(
    int j, float p0x, float p0y, float p0z,
    float dx, float dy, float dz, float L, float s_tof,
    int& ix, int& iy, int& iz, float& e)
{
#pragma clang fp contract(off)
    const float t = (j + 0.5f) * (1.0f / 256.0f);
    const float px = p0x + t * dx;
    const float py = p0y + t * dy;
    const float pz = p0z + t * dz;
    const float fx = floorf((px + 160.0f) * 0.5f);
    const float fy = floorf((py + 160.0f) * 0.5f);
    const float fz = floorf((pz + 160.0f) * 0.5f);
    const bool inb = (fx >= 0.0f) & (fx < 160.0f) &
                     (fy >= 0.0f) & (fy < 160.0f) &
                     (fz >= 0.0f) & (fz < 160.0f);
    const float s = (t - 0.5f) * L;
    const float u = (s - s_tof) * INV_SIGMA;   // fast: mul, not strict div
    e = 0.5f * (u * u);
    if (inb & (e < 10.0f)) {
        ix = (int)fx; iy = (int)fy; iz = (int)fz;
        return true;
    }
    return false;
}

__device__ __forceinline__ void lor_window(
    float p0x, float p0y, float p0z, float dx, float dy, float dz,
    float L, float s_tof, int& j0, int& j1)
{
#pragma clang fp contract(off)
    const float SIGMA = (float)(45.0 / 2.355);
    const float CUTS  = 4.4721360f * SIGMA;      // e<10 support
    const float invL = 1.0f / L;
    float t0 = 0.5f + (s_tof - CUTS) * invL;
    float t1 = 0.5f + (s_tof + CUTS) * invL;
    if (t0 > t1) { const float tmp = t0; t0 = t1; t1 = tmp; }
    const float pc[3] = {p0x, p0y, p0z};
    const float dc[3] = {dx, dy, dz};
    #pragma unroll
    for (int a = 0; a < 3; ++a) {
        if (dc[a] != 0.0f) {
            const float inv = 1.0f / dc[a];
            const float ta = (-160.0f - pc[a]) * inv;
            const float tb = ( 160.0f - pc[a]) * inv;
            t0 = fmaxf(t0, fminf(ta, tb));
            t1 = fminf(t1, fmaxf(ta, tb));
        } else if (pc[a] < -160.0f || pc[a] >= 160.0f) t1 = -1.0f;
    }
    t0 = fmaxf(t0, 0.0f);
    t1 = fminf(t1, 1.0f);
    j0 = (int)floorf(t0 * 256.0f - 0.5f) - 2;
    j1 = (int)ceilf (t1 * 256.0f - 0.5f) + 2;
    if (!(t0 <= t1)) { j0 = 0; j1 = -1; }
    j0 = max(j0, 0);
    j1 = min(j1, NSTEPS - 1);
}

// ---- emission: one wave per LOR; run-length compaction.
//      mode 0 (tier A): forward p[lor] + per-sample payload samples[lor*256+j]
//        + DIRECT item write at items[key][rep][tr] where tr is the hist
//        atomicAdd return (the slot IS final — no scan, no scatter).
//      mode 1 (tier C phase 0): counts only + p.
//      mode 2 (tier C phase 1): cursor atomics, flat item layout.
//      NOTE (R9 lesson): the chg-ballot MUST be taken at full-wave scope.
//      Inside `if (chg && valid)` the exec mask drops chg-but-invalid lanes,
//      whose bits mark run terminations at valid->invalid boundaries; losing
//      them overextends len into unwritten payload (absmax 2134 failure).
__global__ __launch_bounds__(256) void emit_kernel(
    const float* __restrict__ image,
    const float* __restrict__ lors, LorT* __restrict__ lortab,
    int* __restrict__ histcur, unsigned* __restrict__ items,
    float* __restrict__ p, unsigned* __restrict__ samples,
    int n, int mode)
{
#pragma clang fp contract(off)
    const int wave = (int)((blockIdx.x * blockDim.x + threadIdx.x) >> 6);
    const int lane = threadIdx.x & 63;
    if (wave >= n) return;
    const int rep = (int)(blockIdx.x & (NREP - 1));

    float p0x, p0y, p0z, tof, dx, dy, dz, L;
    if (mode != 2) {
        const float* l = lors + (size_t)wave * 7;
        p0x = l[0]; p0y = l[1]; p0z = l[2];
        dx = l[3] - p0x; dy = l[4] - p0y; dz = l[5] - p0z; tof = l[6];
        L = sqrtf(dx * dx + dy * dy + dz * dz);
        if (lane == 0) {
            lortab[wave].a = make_float4(p0x, p0y, p0z, tof);
            lortab[wave].b = make_float4(dx, dy, dz, L);
        }
    } else {
        const float4 A = lortab[wave].a, B = lortab[wave].b;
        p0x = A.x; p0y = A.y; p0z = A.z; tof = A.w;
        dx  = B.x; dy  = B.y; dz  = B.z; L   = B.w;
    }
    const float s_tof = tof * 0.15f;
    const float dl = L * (1.0f / 256.0f);
    int j0, j1;
    lor_window(p0x, p0y, p0z, dx, dy, dz, L, s_tof, j0, j1);
    const int nk = (j1 - j0 + 64) >> 6;

    float psum = 0.0f;
    for (int k = 0; k < nk; ++k) {
        const int j = j0 + lane + (k << 6);
        int ix, iy, iz; float e;
        const bool valid = (j <= j1) &&
            sample_vox(j, p0x, p0y, p0z, dx, dy, dz, L, s_tof, ix, iy, iz, e);
        if (mode != 2) {
            if (valid) {
                const float w = __expf(-e) * dl;
                psum += image[ix * 25600 + iy * 160 + iz] * w;
                if (samples) {
                    const unsigned lidx = (unsigned)((ix & 7) << 6)
                                        | (unsigned)((iy & 7) << 3)
                                        | (unsigned)(iz & 7);
                    const unsigned hb =
                        (unsigned)__half_as_ushort(__float2half(w));
                    samples[(size_t)wave * 256 + j] = (lidx << 16) | hb;
                }
            }
        }
        const unsigned key = valid
            ? (unsigned)((ix >> 3) * 400 + (iy >> 3) * 20 + (iz >> 3))
            : 0xFFFFFFFFu;
        const unsigned prev = __shfl_up(key, 1, 64);
        const bool chg = (lane == 0) || (prev != key);
        const unsigned long long cm = __ballot(chg);   // FULL-WAVE scope
        if (chg && valid) {
            const unsigned long long above = cm & ~((2ULL << lane) - 1ULL);
            const int nxt = above ? (__ffsll((unsigned long long)above) - 1) : 64;
            const int len = nxt - lane;                 // 1..64
            const unsigned word = ((unsigned)wave << 14)
                                | ((unsigned)j << 6) | (unsigned)(len - 1);
            if (mode == 0) {
                const int tr = atomicAdd(&histcur[rep * NTILES + (int)key], 1);
                if (tr < CAP_R)
                    items[((size_t)key * NREP + rep) * CAP_R + tr] = word;
            } else if (mode == 1) {
                atomicAdd(&histcur[rep * NTILES + (int)key], 1);
            } else {
                const int slot = atomicAdd(&histcur[(int)key], 1);
                if (slot < ITEM_CAP) items[slot] = word;
            }
        }
    }
    if (mode != 2) {
        #pragma unroll
        for (int off = 32; off >= 1; off >>= 1) psum += __shfl_xor(psum, off, 64);
        if (lane == 0) p[wave] = psum;
    }
}

// ---- pass B v5 (tier A): block per tile; WAVE-per-item, LANE-per-sample.
//      The item index is wave-uniform; item word + pv are broadcast loads;
//      all len<=64 lanes fetch sp[lane] in one coalesced transaction and
//      issue one exec-masked LDS atomic. Removes the serial len-loop
//      divergence (R10 post-mortem: tileB was ~100us in EVERY version
//      because wave time = max(len) with a dependent load chain per item).
__global__ __launch_bounds__(256) void tileB3_kernel(
    const float* __restrict__ image, const float* __restrict__ effmap,
    const float* __restrict__ p, const int* __restrict__ hist8,
    const unsigned* __restrict__ items, const unsigned* __restrict__ samples,
    float* __restrict__ out)
{
    const int b = blockIdx.x;
    const int t = threadIdx.x;
    const int wid  = t >> 6;
    const int lane = t & 63;
    const int tx0 = (b / 400) << 3, ty0 = ((b / 20) % 20) << 3, tz0 = (b % 20) << 3;
    // per-replica counts and prefix (compile-time register indices only)
    int pre[NREP]; int tot = 0;
    #pragma unroll
    for (int r = 0; r < NREP; ++r) {
        int c = hist8[r * NTILES + b];
        c = min(c, CAP_R);
        pre[r] = tot; tot += c;
    }
    if (tot == 0) {                       // uncovered tile: bp = 0 -> out = 0
        for (int v = t; v < 512; v += 256) {
            const int lx = v >> 6, ly = (v >> 3) & 7, lz = v & 7;
            out[(size_t)(tx0 + lx) * 25600 + (ty0 + ly) * 160 + (tz0 + lz)] = 0.0f;
        }
        return;
    }
    __shared__ float acc[512];
    for (int v = t; v < 512; v += 256) acc[v] = 0.0f;
    __syncthreads();
    for (int idx = wid; idx < tot; idx += 4) {      // 4 waves/block
        // select replica: largest r with pre[r] <= idx (static indices)
        int r = 0, base = 0;
        #pragma unroll
        for (int rr = 1; rr < NREP; ++rr) {
            const bool g = (idx >= pre[rr]);
            r    = g ? rr      : r;
            base = g ? pre[rr] : base;
        }
        const unsigned it =
            items[((size_t)b * NREP + r) * CAP_R + (idx - base)];   // broadcast
        const int lor = (int)(it >> 14);
        const int js  = (int)((it >> 6) & 255);
        const int len = (int)(it & 63) + 1;
        const float pv = p[lor];                                    // broadcast
        if (lane < len) {
            const unsigned word = samples[(size_t)lor * 256 + js + lane];
            const float w = __half2float(
                __ushort_as_half((unsigned short)(word & 0xFFFFu)));
            atomicAdd(&acc[(word >> 16) & 511u], pv * w);
        }
    }
    __syncthreads();
    for (int v = t; v < 512; v += 256) {
        const int lx = v >> 6, ly = (v >> 3) & 7, lz = v & 7;
        const size_t g = (size_t)(tx0 + lx) * 25600 + (ty0 + ly) * 160 + (tz0 + lz);
        out[g] = image[g] / (effmap[g] + 1e-8f) * acc[v];
    }
}

// ---- scan stage (tier C fallback only) ----
__global__ __launch_bounds__(256) void reduce_kernel(
    const int* __restrict__ hist8, int* __restrict__ tot)
{
    const int k = blockIdx.x * blockDim.x + threadIdx.x;
    if (k >= NTILES) return;
    int s = 0;
    #pragma unroll
    for (int r = 0; r < NREP; ++r) s += hist8[r * NTILES + k];
    tot[k] = s;
}

__global__ __launch_bounds__(1024) void scan_kernel(
    const int* __restrict__ tot, int* __restrict__ offs)
{
    __shared__ int part[1024];
    const int t = threadIdx.x;
    const int base = t * 8;
    int loc[8]; int s = 0;
    #pragma unroll
    for (int i = 0; i < 8; ++i) {
        const int h = (base + i < NTILES) ? tot[base + i] : 0;
        loc[i] = s; s += h;
    }
    part[t] = s;
    __syncthreads();
    for (int off = 1; off < 1024; off <<= 1) {
        int v = 0;
        if (t >= off) v = part[t - off];
        __syncthreads();
        part[t] += v;
        __syncthreads();
    }
    const int excl = (t > 0) ? part[t - 1] : 0;
    #pragma unroll
    for (int i = 0; i < 8; ++i)
        if (base + i < NTILES) offs[base + i] = excl + loc[i];
    if (t == 1023) offs[NTILES] = part[1023];
}

__global__ __launch_bounds__(256) void base_kernel(
    const int* __restrict__ offs, int* __restrict__ cursor)
{
    const int k = blockIdx.x * blockDim.x + threadIdx.x;
    if (k >= NTILES) return;
    cursor[k] = offs[k];
}

// ---- pass B v1 (tier C fallback): re-traces samples, flat items ----
__global__ __launch_bounds__(256) void tileB_kernel(
    const float* __restrict__ image, const float* __restrict__ effmap,
    const LorT* __restrict__ lortab, const int* __restrict__ offs,
    const unsigned* __restrict__ items, const float* __restrict__ p,
    float* __restrict__ out)
{
    const int b = blockIdx.x;
    const int i0 = offs[b], i1 = min(offs[b + 1], ITEM_CAP);
    const int tx0 = (b / 400) << 3, ty0 = ((b / 20) % 20) << 3, tz0 = (b % 20) << 3;
    const int t = threadIdx.x;
    if (i0 >= i1) {
        for (int v = t; v < 512; v += 256) {
            const int lx = v >> 6, ly = (v >> 3) & 7, lz = v & 7;
            out[(size_t)(tx0 + lx) * 25600 + (ty0 + ly) * 160 + (tz0 + lz)] = 0.0f;
        }
        return;
    }
    __shared__ float acc[512];
    for (int v = t; v < 512; v += 256) acc[v] = 0.0f;
    __syncthreads();
    for (int idx = i0 + t; idx < i1; idx += 256) {
        const unsigned it = items[idx];
        const int lor = (int)(it >> 14);
        const int js  = (int)((it >> 6) & 255);
        const int len = (int)(it & 63) + 1;
        const float4 A = lortab[lor].a, B = lortab[lor].b;
        const float dl = B.w * (1.0f / 256.0f);
        const float s_tof = A.w * 0.15f;
        const float pv = p[lor];
        for (int m = 0; m < len; ++m) {
            int ix, iy, iz; float e;
            if (sample_vox(js + m, A.x, A.y, A.z, B.x, B.y, B.z, B.w, s_tof,
                           ix, iy, iz, e)) {
                const int lx = ix - tx0, ly = iy - ty0, lz = iz - tz0;
                if ((unsigned)lx < 8u && (unsigned)ly < 8u && (unsigned)lz < 8u)
                    atomicAdd(&acc[(lx << 6) | (ly << 3) | lz],
                              pv * (__expf(-e) * dl));
            }
        }
    }
    __syncthreads();
    for (int v = t; v < 512; v += 256) {
        const int lx = v >> 6, ly = (v >> 3) & 7, lz = v & 7;
        const size_t g = (size_t)(tx0 + lx) * 25600 + (ty0 + ly) * 160 + (tz0 + lz);
        out[g] = image[g] / (effmap[g] + 1e-8f) * acc[v];
    }
}

// ---- fallback: direct trace with global atomics ----
__global__ __launch_bounds__(256) void trace_direct_kernel(
    const float* __restrict__ image, const float* __restrict__ lors,
    float* __restrict__ bp, int n_lors)
{
#pragma clang fp contract(off)
    const int wave = (int)((blockIdx.x * blockDim.x + threadIdx.x) >> 6);
    const int lane = threadIdx.x & 63;
    if (wave >= n_lors) return;
    const float* l = lors + (size_t)wave * 7;
    const float p0x = l[0], p0y = l[1], p0z = l[2];
    const float dx = l[3] - p0x, dy = l[4] - p0y, dz = l[5] - p0z;
    const float tof = l[6];
    const float L  = sqrtf(dx * dx + dy * dy + dz * dz);
    const float dl = L * (1.0f / 256.0f);
    const float s_tof = tof * 0.15f;
    int j0, j1;
    lor_window(p0x, p0y, p0z, dx, dy, dz, L, s_tof, j0, j1);
    const int nk = (j1 - j0 + 64) >> 6;
    if (nk <= 0) return;
    int flat[4]; float w[4]; float psum = 0.0f;
    for (int k = 0; k < nk; ++k) {
        const int j = j0 + lane + (k << 6);
        int ix, iy, iz; float e; float wk = 0.0f; int fl = 0;
        if (j <= j1 &&
            sample_vox(j, p0x, p0y, p0z, dx, dy, dz, L, s_tof, ix, iy, iz, e)) {
            wk = __expf(-e) * dl;
            fl = ix * 25600 + iy * 160 + iz;
            psum += image[fl] * wk;
        }
        flat[k] = fl; w[k] = wk;
    }
    #pragma unroll
    for (int off = 32; off >= 1; off >>= 1) psum += __shfl_xor(psum, off, 64);
    for (int k = 0; k < nk; ++k)
        if (w[k] > 0.0f) atomicAdd(&bp[flat[k]], psum * w[k]);
}

__global__ __launch_bounds__(256) void finalize_kernel(
    const float4* __restrict__ image, const float4* __restrict__ effmap,
    float4* __restrict__ out, int n4)
{
    const int i = blockIdx.x * blockDim.x + threadIdx.x;
    if (i >= n4) return;
    const float4 im = image[i];
    const float4 ef = effmap[i];
    float4 b = out[i];
    b.x = im.x / (ef.x + 1e-8f) * b.x;
    b.y = im.y / (ef.y + 1e-8f) * b.y;
    b.z = im.z / (ef.z + 1e-8f) * b.z;
    b.w = im.w / (ef.w + 1e-8f) * b.w;
    out[i] = b;
}

extern "C" void kernel_launch(void* const* d_in, const int* in_sizes, int n_in,
                              void* d_out, int out_size, void* d_ws, size_t ws_size,
                              hipStream_t stream) {
    const float* image  = (const float*)d_in[0];
    const float* effmap = (const float*)d_in[1];
    const float* lors   = (const float*)d_in[2];
    float* out = (float*)d_out;
    const int n = in_sizes[2] / 7;

    char* ws = (char*)d_ws;
    const size_t hist_off   = 0;                                   // NREP*NTILES
    const size_t tot_off    = hist_off + (size_t)NREP * NTILES * 4;
    const size_t offs_off   = tot_off + 32768;
    const size_t cursor_off = offs_off + 32768;
    const size_t p_off      = cursor_off + 32768;
    const size_t lortab_off = p_off + (((size_t)n * 4 + 255) & ~(size_t)255);
    const size_t items_off  = lortab_off + (size_t)n * sizeof(LorT);
    // tier A: tiled items + samples payload
    const size_t itemsA_sz  = (size_t)NTILES * NREP * CAP_R * 4;   // 65.5 MB
    const size_t smp_off    = items_off + itemsA_sz;
    const size_t total_A    = smp_off + (size_t)n * 256 * 4;
    // tier C: flat items, no payload
    const size_t total_C    = items_off + (size_t)ITEM_CAP * 4;

    const int tileGrid = (NTILES + 255) / 256;

    if (ws_size >= total_A && n > 0 && n < (1 << 17)) {
        int*      hist8  = (int*)(ws + hist_off);
        float*    p      = (float*)(ws + p_off);
        LorT*     lortab = (LorT*)(ws + lortab_off);
        unsigned* items  = (unsigned*)(ws + items_off);
        unsigned* samples = (unsigned*)(ws + smp_off);

        hipMemsetAsync(hist8, 0, (size_t)NREP * NTILES * sizeof(int), stream);

        const int blocksE = (n + 3) / 4;   // 4 waves/block, wave per LOR
        emit_kernel<<<blocksE, 256, 0, stream>>>(image, lors, lortab, hist8,
                                                 items, p, samples, n, 0);
        tileB3_kernel<<<NTILES, 256, 0, stream>>>(image, effmap, p, hist8,
                                                  items, samples, out);
    } else if (ws_size >= total_C && n > 0 && n < (1 << 17)) {
        int*      hist8  = (int*)(ws + hist_off);
        int*      tot    = (int*)(ws + tot_off);
        int*      offs   = (int*)(ws + offs_off);
        int*      cursor = (int*)(ws + cursor_off);
        float*    p      = (float*)(ws + p_off);
        LorT*     lortab = (LorT*)(ws + lortab_off);
        unsigned* items  = (unsigned*)(ws + items_off);

        hipMemsetAsync(hist8, 0, (size_t)NREP * NTILES * sizeof(int), stream);

        const int blocksE = (n + 3) / 4;
        emit_kernel<<<blocksE, 256, 0, stream>>>(image, lors, lortab, hist8,
                                                 items, p, nullptr, n, 1);
        reduce_kernel<<<tileGrid, 256, 0, stream>>>(hist8, tot);
        scan_kernel<<<1, 1024, 0, stream>>>(tot, offs);
        base_kernel<<<tileGrid, 256, 0, stream>>>(offs, cursor);
        emit_kernel<<<blocksE, 256, 0, stream>>>(image, lors, lortab, cursor,
                                                 items, p, nullptr, n, 2);
        tileB_kernel<<<NTILES, 256, 0, stream>>>(image, effmap, lortab, offs,
                                                 items, p, out);
    } else {
        hipMemsetAsync(out, 0, (size_t)NVOX * sizeof(float), stream);
        if (n > 0)
            trace_direct_kernel<<<(n + 3) / 4, 256, 0, stream>>>(image, lors, out, n);
        const int n4 = NVOX / 4;
        finalize_kernel<<<(n4 + 255) / 256, 256, 0, stream>>>(
            (const float4*)image, (const float4*)effmap, (float4*)out, n4);
    }
}

// Round 12
// 187.895 us; speedup vs baseline: 1.3066x; 1.3066x over previous
//
#include <hip/hip_runtime.h>
#include <hip/hip_fp16.h>
#include <math.h>

#define NSTEPS 256
#define GRIDN  160
#define NVOX   (160 * 160 * 160)
#define NTPA   20                  // tiles per axis (8^3-voxel tiles)
#define NTILES (NTPA * NTPA * NTPA)
#define NREP   8                   // bucket/hist replicas (~per-XCD)
#define CAP_S  512                 // sample slots per (tile, replica)
#define ITEM_CAP (4 * 1024 * 1024)

#define INV_SIGMA 0.05233333f      // 2.355/45, fast path (weight only)

struct LorT { float4 a; float4 b; };   // a: p0.xyz, tof ; b: d.xyz, L

// ---- strict voxel path (contract OFF: bit-match f32 numpy floor decisions)
//      + fast validity e (weight tolerance is huge; predicate shared by all users)
__device__ __forceinline__ bool sample_vox(
    int j, float p0x, float p0y, float p0z,
    float dx, float dy, float dz, float L, float s_tof,
    int& ix, int& iy, int& iz, float& e)
{
#pragma clang fp contract(off)
    const float t = (j + 0.5f) * (1.0f / 256.0f);
    const float px = p0x + t * dx;
    const float py = p0y + t * dy;
    const float pz = p0z + t * dz;
    const float fx = floorf((px + 160.0f) * 0.5f);
    const float fy = floorf((py + 160.0f) * 0.5f);
    const float fz = floorf((pz + 160.0f) * 0.5f);
    const bool inb = (fx >= 0.0f) & (fx < 160.0f) &
                     (fy >= 0.0f) & (fy < 160.0f) &
                     (fz >= 0.0f) & (fz < 160.0f);
    const float s = (t - 0.5f) * L;
    const float u = (s - s_tof) * INV_SIGMA;   // fast: mul, not strict div
    e = 0.5f * (u * u);
    if (inb & (e < 10.0f)) {
        ix = (int)fx; iy = (int)fy; iz = (int)fz;
        return true;
    }
    return false;
}

__device__ __forceinline__ void lor_window(
    float p0x, float p0y, float p0z, float dx, float dy, float dz,
    float L, float s_tof, int& j0, int& j1)
{
#pragma clang fp contract(off)
    const float SIGMA = (float)(45.0 / 2.355);
    const float CUTS  = 4.4721360f * SIGMA;      // e<10 support
    const float invL = 1.0f / L;
    float t0 = 0.5f + (s_tof - CUTS) * invL;
    float t1 = 0.5f + (s_tof + CUTS) * invL;
    if (t0 > t1) { const float tmp = t0; t0 = t1; t1 = tmp; }
    const float pc[3] = {p0x, p0y, p0z};
    const float dc[3] = {dx, dy, dz};
    #pragma unroll
    for (int a = 0; a < 3; ++a) {
        if (dc[a] != 0.0f) {
            const float inv = 1.0f / dc[a];
            const float ta = (-160.0f - pc[a]) * inv;
            const float tb = ( 160.0f - pc[a]) * inv;
            t0 = fmaxf(t0, fminf(ta, tb));
            t1 = fminf(t1, fmaxf(ta, tb));
        } else if (pc[a] < -160.0f || pc[a] >= 160.0f) t1 = -1.0f;
    }
    t0 = fmaxf(t0, 0.0f);
    t1 = fminf(t1, 1.0f);
    j0 = (int)floorf(t0 * 256.0f - 0.5f) - 2;
    j1 = (int)ceilf (t1 * 256.0f - 0.5f) + 2;
    if (!(t0 <= t1)) { j0 = 0; j1 = -1; }
    j0 = max(j0, 0);
    j1 = min(j1, NSTEPS - 1);
}

// ---- tier A emission: one wave per LOR, two register-resident passes.
//      Pass 1 (k-slots, static unroll <=4): trace, cache (w, key|lidx) in
//      registers, accumulate forward psum. Wave-reduce -> pv on all lanes.
//      Pass 2: run-length segments per k-slot; the segment LEADER reserves
//      len bucket slots with ONE atomicAdd on scnt[rep][key] (1M atomics,
//      proven hidden under emit compute); base is shfl-broadcast; each valid
//      lane stores its FINAL bp entry (lidx<<16 | fp16(pv*w)) contiguously.
//      Rare overflow (slot >= CAP_S) -> global atomicAdd into out (bp).
//      R9 lesson: all ballots at FULL-WAVE scope.
__global__ __launch_bounds__(256) void emit_bucket_kernel(
    const float* __restrict__ image, const float* __restrict__ lors,
    int* __restrict__ scnt, unsigned* __restrict__ bucket,
    float* __restrict__ out_bp, int n)
{
#pragma clang fp contract(off)
    const int wave = (int)((blockIdx.x * blockDim.x + threadIdx.x) >> 6);
    const int lane = threadIdx.x & 63;
    if (wave >= n) return;
    const int rep = (int)(blockIdx.x & (NREP - 1));

    const float* l = lors + (size_t)wave * 7;
    const float p0x = l[0], p0y = l[1], p0z = l[2];
    const float dx = l[3] - p0x, dy = l[4] - p0y, dz = l[5] - p0z;
    const float tof = l[6];
    const float L  = sqrtf(dx * dx + dy * dy + dz * dz);
    const float s_tof = tof * 0.15f;
    const float dl = L * (1.0f / 256.0f);
    int j0, j1;
    lor_window(p0x, p0y, p0z, dx, dy, dz, L, s_tof, j0, j1);

    // pass 1: trace into registers (full unroll -> static indices, rule #20)
    float    wk[4];
    unsigned kk[4];                      // (key<<9)|lidx, 0xFFFFFFFF invalid
    float psum = 0.0f;
    #pragma unroll
    for (int k = 0; k < 4; ++k) {
        wk[k] = 0.0f; kk[k] = 0xFFFFFFFFu;
        const int j = j0 + lane + (k << 6);
        if (j <= j1) {
            int ix, iy, iz; float e;
            if (sample_vox(j, p0x, p0y, p0z, dx, dy, dz, L, s_tof,
                           ix, iy, iz, e)) {
                const float w = __expf(-e) * dl;
                wk[k] = w;
                kk[k] = (((unsigned)((ix >> 3) * 400 + (iy >> 3) * 20
                                     + (iz >> 3))) << 9)
                      | (unsigned)(((ix & 7) << 6) | ((iy & 7) << 3) | (iz & 7));
                psum += image[ix * 25600 + iy * 160 + iz] * w;
            }
        }
    }
    #pragma unroll
    for (int off = 32; off >= 1; off >>= 1) psum += __shfl_xor(psum, off, 64);
    // psum == pv on all lanes now

    // pass 2: segment-reserved bucket writes
    #pragma unroll
    for (int k = 0; k < 4; ++k) {
        const bool valid = (kk[k] != 0xFFFFFFFFu);
        const unsigned key = kk[k] >> 9;           // sentinel -> 0x7FFFFF
        const unsigned prev = __shfl_up(key, 1, 64);
        const bool chg = (lane == 0) || (prev != key);
        const unsigned long long cm = __ballot(chg);            // FULL WAVE
        const unsigned long long below = cm & ((2ULL << lane) - 1ULL);
        const int leader = 63 - __clzll((long long)below);      // below != 0
        const unsigned long long above = cm & ~((2ULL << lane) - 1ULL);
        const int nxt = above ? (__ffsll((long long)above) - 1) : 64;
        int tr = 0;
        if (chg && valid)
            tr = atomicAdd(&scnt[rep * NTILES + (int)key], nxt - lane);
        tr = __shfl(tr, leader, 64);
        if (valid) {
            const int slot = tr + (lane - leader);
            const float v = psum * wk[k];
            if (slot < CAP_S) {
                const unsigned entry = ((kk[k] & 511u) << 16)
                    | (unsigned)__half_as_ushort(__float2half(v));
                bucket[((size_t)key * NREP + rep) * CAP_S + slot] = entry;
            } else {                       // rare overflow -> global bp atomic
                const int ky = (int)key;
                const int tx = ky / 400, ty = (ky / 20) % 20, tz = ky % 20;
                const int lidx = (int)(kk[k] & 511u);
                const size_t g = (size_t)(tx * 8 + (lidx >> 6)) * 25600
                               + (size_t)(ty * 8 + ((lidx >> 3) & 7)) * 160
                               + (size_t)(tz * 8 + (lidx & 7));
                atomicAdd(&out_bp[g], v);
            }
        }
    }
}

// ---- tier A pass B: thread-per-sample over the tile's bucket ranges.
//      One coalesced 4B load -> unpack -> LDS atomic. No items, no lortab,
//      no p, no dependent chains. Epilogue folds in overflow bp from out.
__global__ __launch_bounds__(256) void tileB4_kernel(
    const float* __restrict__ image, const float* __restrict__ effmap,
    const int* __restrict__ scnt, const unsigned* __restrict__ bucket,
    float* __restrict__ out)
{
    const int b = blockIdx.x;
    const int t = threadIdx.x;
    const int tx0 = (b / 400) << 3, ty0 = ((b / 20) % 20) << 3, tz0 = (b % 20) << 3;
    int pre[NREP]; int tot = 0;
    #pragma unroll
    for (int r = 0; r < NREP; ++r) {
        int c = scnt[r * NTILES + b];
        c = min(c, CAP_S);
        pre[r] = tot; tot += c;
    }
    if (tot == 0) return;      // out stays 0 (memset; no overflow possible)
    __shared__ float acc[512];
    for (int v = t; v < 512; v += 256) acc[v] = 0.0f;
    __syncthreads();
    for (int idx = t; idx < tot; idx += 256) {
        int r = 0, base = 0;
        #pragma unroll
        for (int rr = 1; rr < NREP; ++rr) {
            const bool g = (idx >= pre[rr]);
            r    = g ? rr      : r;
            base = g ? pre[rr] : base;
        }
        const unsigned e = bucket[((size_t)b * NREP + r) * CAP_S + (idx - base)];
        atomicAdd(&acc[(e >> 16) & 511u],
                  __half2float(__ushort_as_half((unsigned short)(e & 0xFFFFu))));
    }
    __syncthreads();
    for (int v = t; v < 512; v += 256) {
        const int lx = v >> 6, ly = (v >> 3) & 7, lz = v & 7;
        const size_t g = (size_t)(tx0 + lx) * 25600 + (ty0 + ly) * 160 + (tz0 + lz);
        out[g] = image[g] / (effmap[g] + 1e-8f) * (acc[v] + out[g]);
    }
}

// ---- tier C emission (fallback, unchanged from R10 passing path) ----
__global__ __launch_bounds__(256) void emit_kernel(
    const float* __restrict__ image,
    const float* __restrict__ lors, LorT* __restrict__ lortab,
    int* __restrict__ histcur, unsigned* __restrict__ items,
    float* __restrict__ p,
    int n, int mode)
{
#pragma clang fp contract(off)
    const int wave = (int)((blockIdx.x * blockDim.x + threadIdx.x) >> 6);
    const int lane = threadIdx.x & 63;
    if (wave >= n) return;
    const int rep = (int)(blockIdx.x & (NREP - 1));

    float p0x, p0y, p0z, tof, dx, dy, dz, L;
    if (mode != 2) {
        const float* l = lors + (size_t)wave * 7;
        p0x = l[0]; p0y = l[1]; p0z = l[2];
        dx = l[3] - p0x; dy = l[4] - p0y; dz = l[5] - p0z; tof = l[6];
        L = sqrtf(dx * dx + dy * dy + dz * dz);
        if (lane == 0) {
            lortab[wave].a = make_float4(p0x, p0y, p0z, tof);
            lortab[wave].b = make_float4(dx, dy, dz, L);
        }
    } else {
        const float4 A = lortab[wave].a, B = lortab[wave].b;
        p0x = A.x; p0y = A.y; p0z = A.z; tof = A.w;
        dx  = B.x; dy  = B.y; dz  = B.z; L   = B.w;
    }
    const float s_tof = tof * 0.15f;
    const float dl = L * (1.0f / 256.0f);
    int j0, j1;
    lor_window(p0x, p0y, p0z, dx, dy, dz, L, s_tof, j0, j1);
    const int nk = (j1 - j0 + 64) >> 6;

    float psum = 0.0f;
    for (int k = 0; k < nk; ++k) {
        const int j = j0 + lane + (k << 6);
        int ix, iy, iz; float e;
        const bool valid = (j <= j1) &&
            sample_vox(j, p0x, p0y, p0z, dx, dy, dz, L, s_tof, ix, iy, iz, e);
        if (mode != 2) {
            if (valid)
                psum += image[ix * 25600 + iy * 160 + iz] * (__expf(-e) * dl);
        }
        const unsigned key = valid
            ? (unsigned)((ix >> 3) * 400 + (iy >> 3) * 20 + (iz >> 3))
            : 0xFFFFFFFFu;
        const unsigned prev = __shfl_up(key, 1, 64);
        const bool chg = (lane == 0) || (prev != key);
        const unsigned long long cm = __ballot(chg);   // FULL-WAVE scope
        if (chg && valid) {
            const unsigned long long above = cm & ~((2ULL << lane) - 1ULL);
            const int nxt = above ? (__ffsll((unsigned long long)above) - 1) : 64;
            const int len = nxt - lane;                 // 1..64
            const unsigned word = ((unsigned)wave << 14)
                                | ((unsigned)j << 6) | (unsigned)(len - 1);
            if (mode == 1) {
                atomicAdd(&histcur[rep * NTILES + (int)key], 1);
            } else if (mode == 2) {
                const int slot = atomicAdd(&histcur[(int)key], 1);
                if (slot < ITEM_CAP) items[slot] = word;
            }
        }
    }
    if (mode != 2) {
        #pragma unroll
        for (int off = 32; off >= 1; off >>= 1) psum += __shfl_xor(psum, off, 64);
        if (lane == 0) p[wave] = psum;
    }
}

// ---- scan stage (tier C fallback only) ----
__global__ __launch_bounds__(256) void reduce_kernel(
    const int* __restrict__ hist8, int* __restrict__ tot)
{
    const int k = blockIdx.x * blockDim.x + threadIdx.x;
    if (k >= NTILES) return;
    int s = 0;
    #pragma unroll
    for (int r = 0; r < NREP; ++r) s += hist8[r * NTILES + k];
    tot[k] = s;
}

__global__ __launch_bounds__(1024) void scan_kernel(
    const int* __restrict__ tot, int* __restrict__ offs)
{
    __shared__ int part[1024];
    const int t = threadIdx.x;
    const int base = t * 8;
    int loc[8]; int s = 0;
    #pragma unroll
    for (int i = 0; i < 8; ++i) {
        const int h = (base + i < NTILES) ? tot[base + i] : 0;
        loc[i] = s; s += h;
    }
    part[t] = s;
    __syncthreads();
    for (int off = 1; off < 1024; off <<= 1) {
        int v = 0;
        if (t >= off) v = part[t - off];
        __syncthreads();
        part[t] += v;
        __syncthreads();
    }
    const int excl = (t > 0) ? part[t - 1] : 0;
    #pragma unroll
    for (int i = 0; i < 8; ++i)
        if (base + i < NTILES) offs[base + i] = excl + loc[i];
    if (t == 1023) offs[NTILES] = part[1023];
}

__global__ __launch_bounds__(256) void base_kernel(
    const int* __restrict__ offs, int* __restrict__ cursor)
{
    const int k = blockIdx.x * blockDim.x + threadIdx.x;
    if (k >= NTILES) return;
    cursor[k] = offs[k];
}

// ---- tier C pass B (re-traces samples, flat items) ----
__global__ __launch_bounds__(256) void tileB_kernel(
    const float* __restrict__ image, const float* __restrict__ effmap,
    const LorT* __restrict__ lortab, const int* __restrict__ offs,
    const unsigned* __restrict__ items, const float* __restrict__ p,
    float* __restrict__ out)
{
    const int b = blockIdx.x;
    const int i0 = offs[b], i1 = min(offs[b + 1], ITEM_CAP);
    const int tx0 = (b / 400) << 3, ty0 = ((b / 20) % 20) << 3, tz0 = (b % 20) << 3;
    const int t = threadIdx.x;
    if (i0 >= i1) {
        for (int v = t; v < 512; v += 256) {
            const int lx = v >> 6, ly = (v >> 3) & 7, lz = v & 7;
            out[(size_t)(tx0 + lx) * 25600 + (ty0 + ly) * 160 + (tz0 + lz)] = 0.0f;
        }
        return;
    }
    __shared__ float acc[512];
    for (int v = t; v < 512; v += 256) acc[v] = 0.0f;
    __syncthreads();
    for (int idx = i0 + t; idx < i1; idx += 256) {
        const unsigned it = items[idx];
        const int lor = (int)(it >> 14);
        const int js  = (int)((it >> 6) & 255);
        const int len = (int)(it & 63) + 1;
        const float4 A = lortab[lor].a, B = lortab[lor].b;
        const float dl = B.w * (1.0f / 256.0f);
        const float s_tof = A.w * 0.15f;
        const float pv = p[lor];
        for (int m = 0; m < len; ++m) {
            int ix, iy, iz; float e;
            if (sample_vox(js + m, A.x, A.y, A.z, B.x, B.y, B.z, B.w, s_tof,
                           ix, iy, iz, e)) {
                const int lx = ix - tx0, ly = iy - ty0, lz = iz - tz0;
                if ((unsigned)lx < 8u && (unsigned)ly < 8u && (unsigned)lz < 8u)
                    atomicAdd(&acc[(lx << 6) | (ly << 3) | lz],
                              pv * (__expf(-e) * dl));
            }
        }
    }
    __syncthreads();
    for (int v = t; v < 512; v += 256) {
        const int lx = v >> 6, ly = (v >> 3) & 7, lz = v & 7;
        const size_t g = (size_t)(tx0 + lx) * 25600 + (ty0 + ly) * 160 + (tz0 + lz);
        out[g] = image[g] / (effmap[g] + 1e-8f) * acc[v];
    }
}

// ---- fallback: direct trace with global atomics ----
__global__ __launch_bounds__(256) void trace_direct_kernel(
    const float* __restrict__ image, const float* __restrict__ lors,
    float* __restrict__ bp, int n_lors)
{
#pragma clang fp contract(off)
    const int wave = (int)((blockIdx.x * blockDim.x + threadIdx.x) >> 6);
    const int lane = threadIdx.x & 63;
    if (wave >= n_lors) return;
    const float* l = lors + (size_t)wave * 7;
    const float p0x = l[0], p0y = l[1], p0z = l[2];
    const float dx = l[3] - p0x, dy = l[4] - p0y, dz = l[5] - p0z;
    const float tof = l[6];
    const float L  = sqrtf(dx * dx + dy * dy + dz * dz);
    const float dl = L * (1.0f / 256.0f);
    const float s_tof = tof * 0.15f;
    int j0, j1;
    lor_window(p0x, p0y, p0z, dx, dy, dz, L, s_tof, j0, j1);
    const int nk = (j1 - j0 + 64) >> 6;
    if (nk <= 0) return;
    int flat[4]; float w[4]; float psum = 0.0f;
    for (int k = 0; k < nk; ++k) {
        const int j = j0 + lane + (k << 6);
        int ix, iy, iz; float e; float wk = 0.0f; int fl = 0;
        if (j <= j1 &&
            sample_vox(j, p0x, p0y, p0z, dx, dy, dz, L, s_tof, ix, iy, iz, e)) {
            wk = __expf(-e) * dl;
            fl = ix * 25600 + iy * 160 + iz;
            psum += image[fl] * wk;
        }
        flat[k] = fl; w[k] = wk;
    }
    #pragma unroll
    for (int off = 32; off >= 1; off >>= 1) psum += __shfl_xor(psum, off, 64);
    for (int k = 0; k < nk; ++k)
        if (w[k] > 0.0f) atomicAdd(&bp[flat[k]], psum * w[k]);
}

__global__ __launch_bounds__(256) void finalize_kernel(
    const float4* __restrict__ image, const float4* __restrict__ effmap,
    float4* __restrict__ out, int n4)
{
    const int i = blockIdx.x * blockDim.x + threadIdx.x;
    if (i >= n4) return;
    const float4 im = image[i];
    const float4 ef = effmap[i];
    float4 b = out[i];
    b.x = im.x / (ef.x + 1e-8f) * b.x;
    b.y = im.y / (ef.y + 1e-8f) * b.y;
    b.z = im.z / (ef.z + 1e-8f) * b.z;
    b.w = im.w / (ef.w + 1e-8f) * b.w;
    out[i] = b;
}

extern "C" void kernel_launch(void* const* d_in, const int* in_sizes, int n_in,
                              void* d_out, int out_size, void* d_ws, size_t ws_size,
                              hipStream_t stream) {
    const float* image  = (const float*)d_in[0];
    const float* effmap = (const float*)d_in[1];
    const float* lors   = (const float*)d_in[2];
    float* out = (float*)d_out;
    const int n = in_sizes[2] / 7;

    char* ws = (char*)d_ws;
    const size_t hist_off   = 0;                                   // NREP*NTILES
    const size_t tot_off    = hist_off + (size_t)NREP * NTILES * 4;
    const size_t offs_off   = tot_off + 32768;
    const size_t cursor_off = offs_off + 32768;
    const size_t p_off      = cursor_off + 32768;
    const size_t lortab_off = p_off + (((size_t)n * 4 + 255) & ~(size_t)255);
    const size_t after_fix  = lortab_off + (size_t)n * sizeof(LorT);
    // tier A: per-(tile,rep) sample buckets (final bp entries)
    const size_t bucket_off = after_fix;
    const size_t total_A    = bucket_off
                            + (size_t)NTILES * NREP * CAP_S * 4;   // 131 MB
    // tier C: flat items
    const size_t items_off2 = after_fix;
    const size_t total_C    = items_off2 + (size_t)ITEM_CAP * 4;

    const int tileGrid = (NTILES + 255) / 256;

    if (ws_size >= total_A && n > 0 && n < (1 << 17)) {
        int*      scnt   = (int*)(ws + hist_off);
        unsigned* bucket = (unsigned*)(ws + bucket_off);

        hipMemsetAsync(out, 0, (size_t)NVOX * sizeof(float), stream);
        hipMemsetAsync(scnt, 0, (size_t)NREP * NTILES * sizeof(int), stream);

        const int blocksE = (n + 3) / 4;   // 4 waves/block, wave per LOR
        emit_bucket_kernel<<<blocksE, 256, 0, stream>>>(image, lors, scnt,
                                                        bucket, out, n);
        tileB4_kernel<<<NTILES, 256, 0, stream>>>(image, effmap, scnt,
                                                  bucket, out);
    } else if (ws_size >= total_C && n > 0 && n < (1 << 17)) {
        int*      hist8  = (int*)(ws + hist_off);
        int*      tot    = (int*)(ws + tot_off);
        int*      offs   = (int*)(ws + offs_off);
        int*      cursor = (int*)(ws + cursor_off);
        float*    p      = (float*)(ws + p_off);
        LorT*     lortab = (LorT*)(ws + lortab_off);
        unsigned* items  = (unsigned*)(ws + items_off2);

        hipMemsetAsync(hist8, 0, (size_t)NREP * NTILES * sizeof(int), stream);

        const int blocksE = (n + 3) / 4;
        emit_kernel<<<blocksE, 256, 0, stream>>>(image, lors, lortab, hist8,
                                                 items, p, n, 1);
        reduce_kernel<<<tileGrid, 256, 0, stream>>>(hist8, tot);
        scan_kernel<<<1, 1024, 0, stream>>>(tot, offs);
        base_kernel<<<tileGrid, 256, 0, stream>>>(offs, cursor);
        emit_kernel<<<blocksE, 256, 0, stream>>>(image, lors, lortab, cursor,
                                                 items, p, n, 2);
        tileB_kernel<<<NTILES, 256, 0, stream>>>(image, effmap, lortab, offs,
                                                 items, p, out);
    } else {
        hipMemsetAsync(out, 0, (size_t)NVOX * sizeof(float), stream);
        if (n > 0)
            trace_direct_kernel<<<(n + 3) / 4, 256, 0, stream>>>(image, lors, out, n);
        const int n4 = NVOX / 4;
        finalize_kernel<<<(n4 + 255) / 256, 256, 0, stream>>>(
            (const float4*)image, (const float4*)effmap, (float4*)out, n4);
    }
}

// Round 14
// 178.014 us; speedup vs baseline: 1.3791x; 1.0555x over previous
//
#include <hip/hip_runtime.h>
#include <hip/hip_fp16.h>
#include <math.h>

#define NSTEPS 256
#define GRIDN  160
#define NVOX   (160 * 160 * 160)
#define NTPA   20                  // tiles per axis (8^3-voxel tiles)
#define NTILES (NTPA * NTPA * NTPA)
#define NREP   8                   // bucket/hist replicas (~per-XCD)
#define CAP_S  512                 // sample slots per (tile, replica)
#define OV_CAP 65536               // overflow-entry capacity
#define ITEM_CAP (4 * 1024 * 1024)

#define INV_SIGMA 0.05233333f      // 2.355/45, fast path (weight only)

struct LorT { float4 a; float4 b; };   // a: p0.xyz, tof ; b: d.xyz, L

// ---- strict voxel path (contract OFF: bit-match f32 numpy floor decisions)
__device__ __forceinline__ bool sample_vox(
    int j, float p0x, float p0y, float p0z,
    float dx, float dy, float dz, float L, float s_tof,
    int& ix, int& iy, int& iz, float& e)
{
#pragma clang fp contract(off)
    const float t = (j + 0.5f) * (1.0f / 256.0f);
    const float px = p0x + t * dx;
    const float py = p0y + t * dy;
    const float pz = p0z + t * dz;
    const float fx = floorf((px + 160.0f) * 0.5f);
    const float fy = floorf((py + 160.0f) * 0.5f);
    const float fz = floorf((pz + 160.0f) * 0.5f);
    const bool inb = (fx >= 0.0f) & (fx < 160.0f) &
                     (fy >= 0.0f) & (fy < 160.0f) &
                     (fz >= 0.0f) & (fz < 160.0f);
    const float s = (t - 0.5f) * L;
    const float u = (s - s_tof) * INV_SIGMA;   // fast: mul, not strict div
    e = 0.5f * (u * u);
    if (inb & (e < 10.0f)) {
        ix = (int)fx; iy = (int)fy; iz = (int)fz;
        return true;
    }
    return false;
}

__device__ __forceinline__ void lor_window(
    float p0x, float p0y, float p0z, float dx, float dy, float dz,
    float L, float s_tof, int& j0, int& j1)
{
#pragma clang fp contract(off)
    const float SIGMA = (float)(45.0 / 2.355);
    const float CUTS  = 4.4721360f * SIGMA;      // e<10 support
    const float invL = 1.0f / L;
    float t0 = 0.5f + (s_tof - CUTS) * invL;
    float t1 = 0.5f + (s_tof + CUTS) * invL;
    if (t0 > t1) { const float tmp = t0; t0 = t1; t1 = tmp; }
    const float pc[3] = {p0x, p0y, p0z};
    const float dc[3] = {dx, dy, dz};
    #pragma unroll
    for (int a = 0; a < 3; ++a) {
        if (dc[a] != 0.0f) {
            const float inv = 1.0f / dc[a];
            const float ta = (-160.0f - pc[a]) * inv;
            const float tb = ( 160.0f - pc[a]) * inv;
            t0 = fmaxf(t0, fminf(ta, tb));
            t1 = fminf(t1, fmaxf(ta, tb));
        } else if (pc[a] < -160.0f || pc[a] >= 160.0f) t1 = -1.0f;
    }
    t0 = fmaxf(t0, 0.0f);
    t1 = fminf(t1, 1.0f);
    j0 = (int)floorf(t0 * 256.0f - 0.5f) - 2;
    j1 = (int)ceilf (t1 * 256.0f - 0.5f) + 2;
    if (!(t0 <= t1)) { j0 = 0; j1 = -1; }
    j0 = max(j0, 0);
    j1 = min(j1, NSTEPS - 1);
}

// ---- tier A emission (R12 lineage, passed): one wave per LOR, two
//      register-resident passes. Pass 1: trace + forward psum (wave-reduce).
//      Pass 2: run-length segments; leader reserves len slots with ONE
//      atomicAdd on scnt[rep][key]; base shfl-broadcast; each valid lane
//      stores its FINAL bp entry (lidx<<16 | fp16(pv*w)) contiguously.
//      R14 change: overflow (slot >= CAP_S) goes to a (g, v) list instead of
//      atomics into a zeroed out — this removes the 16 MB out memset AND the
//      epilogue out-read in tileB4. Ballots at FULL-WAVE scope (R9 lesson).
__global__ __launch_bounds__(256) void emit_bucket_kernel(
    const float* __restrict__ image, const float* __restrict__ lors,
    int* __restrict__ scnt, unsigned* __restrict__ bucket,
    unsigned* __restrict__ ovg, float* __restrict__ ovv,
    int* __restrict__ ovcnt, int n)
{
#pragma clang fp contract(off)
    const int wave = (int)((blockIdx.x * blockDim.x + threadIdx.x) >> 6);
    const int lane = threadIdx.x & 63;
    if (wave >= n) return;
    const int rep = (int)(blockIdx.x & (NREP - 1));

    const float* l = lors + (size_t)wave * 7;
    const float p0x = l[0], p0y = l[1], p0z = l[2];
    const float dx = l[3] - p0x, dy = l[4] - p0y, dz = l[5] - p0z;
    const float tof = l[6];
    const float L  = sqrtf(dx * dx + dy * dy + dz * dz);
    const float s_tof = tof * 0.15f;
    const float dl = L * (1.0f / 256.0f);
    int j0, j1;
    lor_window(p0x, p0y, p0z, dx, dy, dz, L, s_tof, j0, j1);

    // pass 1: trace into registers (full unroll -> static indices, rule #20)
    float    wk[4];
    unsigned kk[4];                      // (key<<9)|lidx, 0xFFFFFFFF invalid
    float psum = 0.0f;
    #pragma unroll
    for (int k = 0; k < 4; ++k) {
        wk[k] = 0.0f; kk[k] = 0xFFFFFFFFu;
        const int j = j0 + lane + (k << 6);
        if (j <= j1) {
            int ix, iy, iz; float e;
            if (sample_vox(j, p0x, p0y, p0z, dx, dy, dz, L, s_tof,
                           ix, iy, iz, e)) {
                const float w = __expf(-e) * dl;
                wk[k] = w;
                kk[k] = (((unsigned)((ix >> 3) * 400 + (iy >> 3) * 20
                                     + (iz >> 3))) << 9)
                      | (unsigned)(((ix & 7) << 6) | ((iy & 7) << 3) | (iz & 7));
                psum += image[ix * 25600 + iy * 160 + iz] * w;
            }
        }
    }
    #pragma unroll
    for (int off = 32; off >= 1; off >>= 1) psum += __shfl_xor(psum, off, 64);
    // psum == pv on all lanes now

    // pass 2: segment-reserved bucket writes
    #pragma unroll
    for (int k = 0; k < 4; ++k) {
        const bool valid = (kk[k] != 0xFFFFFFFFu);
        const unsigned key = kk[k] >> 9;           // sentinel -> 0x7FFFFF
        const unsigned prev = __shfl_up(key, 1, 64);
        const bool chg = (lane == 0) || (prev != key);
        const unsigned long long cm = __ballot(chg);            // FULL WAVE
        const unsigned long long below = cm & ((2ULL << lane) - 1ULL);
        const int leader = 63 - __clzll((long long)below);      // below != 0
        const unsigned long long above = cm & ~((2ULL << lane) - 1ULL);
        const int nxt = above ? (__ffsll((long long)above) - 1) : 64;
        int tr = 0;
        if (chg && valid)
            tr = atomicAdd(&scnt[rep * NTILES + (int)key], nxt - lane);
        tr = __shfl(tr, leader, 64);
        if (valid) {
            const int slot = tr + (lane - leader);
            const float v = psum * wk[k];
            if (slot < CAP_S) {
                const unsigned entry = ((kk[k] & 511u) << 16)
                    | (unsigned)__half_as_ushort(__float2half(v));
                bucket[((size_t)key * NREP + rep) * CAP_S + slot] = entry;
            } else {                       // rare overflow -> (g, v) list
                const int ky = (int)key;
                const int tx = ky / 400, ty = (ky / 20) % 20, tz = ky % 20;
                const int lidx = (int)(kk[k] & 511u);
                const unsigned g =
                    (unsigned)((tx * 8 + (lidx >> 6)) * 25600
                             + (ty * 8 + ((lidx >> 3) & 7)) * 160
                             + (tz * 8 + (lidx & 7)));
                const int oi = atomicAdd(ovcnt, 1);
                if (oi < OV_CAP) { ovg[oi] = g; ovv[oi] = v; }
            }
        }
    }
}

// ---- tier A pass B (R12 lineage): thread-per-sample over the tile's bucket
//      ranges. One coalesced 4B load -> unpack -> LDS atomic. R14 change:
//      empty tiles write zeros (no out memset) and the epilogue is a PURE
//      write (no out-read; overflow handled by fold_overflow_kernel).
__global__ __launch_bounds__(256) void tileB4_kernel(
    const float* __restrict__ image, const float* __restrict__ effmap,
    const int* __restrict__ scnt, const unsigned* __restrict__ bucket,
    float* __restrict__ out)
{
    const int b = blockIdx.x;
    const int t = threadIdx.x;
    const int tx0 = (b / 400) << 3, ty0 = ((b / 20) % 20) << 3, tz0 = (b % 20) << 3;
    int pre[NREP]; int tot = 0;
    #pragma unroll
    for (int r = 0; r < NREP; ++r) {
        int c = scnt[r * NTILES + b];
        c = min(c, CAP_S);
        pre[r] = tot; tot += c;
    }
    if (tot == 0) {                       // uncovered tile: bp = 0 -> out = 0
        for (int v = t; v < 512; v += 256) {
            const int lx = v >> 6, ly = (v >> 3) & 7, lz = v & 7;
            out[(size_t)(tx0 + lx) * 25600 + (ty0 + ly) * 160 + (tz0 + lz)] = 0.0f;
        }
        return;
    }
    __shared__ float acc[512];
    for (int v = t; v < 512; v += 256) acc[v] = 0.0f;
    __syncthreads();
    for (int idx = t; idx < tot; idx += 256) {
        int r = 0, base = 0;
        #pragma unroll
        for (int rr = 1; rr < NREP; ++rr) {
            const bool g = (idx >= pre[rr]);
            r    = g ? rr      : r;
            base = g ? pre[rr] : base;
        }
        const unsigned e = bucket[((size_t)b * NREP + r) * CAP_S + (idx - base)];
        atomicAdd(&acc[(e >> 16) & 511u],
                  __half2float(__ushort_as_half((unsigned short)(e & 0xFFFFu))));
    }
    __syncthreads();
    for (int v = t; v < 512; v += 256) {
        const int lx = v >> 6, ly = (v >> 3) & 7, lz = v & 7;
        const size_t g = (size_t)(tx0 + lx) * 25600 + (ty0 + ly) * 160 + (tz0 + lz);
        out[g] = image[g] / (effmap[g] + 1e-8f) * acc[v];
    }
}

// ---- fold rare overflow entries: out[g] += im/(ef+eps) * v (linear) ----
__global__ __launch_bounds__(256) void fold_overflow_kernel(
    const float* __restrict__ image, const float* __restrict__ effmap,
    const unsigned* __restrict__ ovg, const float* __restrict__ ovv,
    const int* __restrict__ ovcnt, float* __restrict__ out)
{
    const int oc = min(*ovcnt, OV_CAP);
    const int gtid = (int)(blockIdx.x * blockDim.x + threadIdx.x);
    const int gsz  = (int)(gridDim.x * blockDim.x);
    for (int i = gtid; i < oc; i += gsz) {
        const unsigned g = ovg[i];
        atomicAdd(&out[g], image[g] / (effmap[g] + 1e-8f) * ovv[i]);
    }
}

// ======== tier C fallback (flat items, two-phase; verified lineage) ========
__global__ __launch_bounds__(256) void emit_kernel(
    const float* __restrict__ image,
    const float* __restrict__ lors, LorT* __restrict__ lortab,
    int* __restrict__ histcur, unsigned* __restrict__ items,
    float* __restrict__ p,
    int n, int mode)
{
#pragma clang fp contract(off)
    const int wave = (int)((blockIdx.x * blockDim.x + threadIdx.x) >> 6);
    const int lane = threadIdx.x & 63;
    if (wave >= n) return;
    const int rep = (int)(blockIdx.x & (NREP - 1));

    float p0x, p0y, p0z, tof, dx, dy, dz, L;
    if (mode != 2) {
        const float* l = lors + (size_t)wave * 7;
        p0x = l[0]; p0y = l[1]; p0z = l[2];
        dx = l[3] - p0x; dy = l[4] - p0y; dz = l[5] - p0z; tof = l[6];
        L = sqrtf(dx * dx + dy * dy + dz * dz);
        if (lane == 0) {
            lortab[wave].a = make_float4(p0x, p0y, p0z, tof);
            lortab[wave].b = make_float4(dx, dy, dz, L);
        }
    } else {
        const float4 A = lortab[wave].a, B = lortab[wave].b;
        p0x = A.x; p0y = A.y; p0z = A.z; tof = A.w;
        dx  = B.x; dy  = B.y; dz  = B.z; L   = B.w;
    }
    const float s_tof = tof * 0.15f;
    const float dl = L * (1.0f / 256.0f);
    int j0, j1;
    lor_window(p0x, p0y, p0z, dx, dy, dz, L, s_tof, j0, j1);
    const int nk = (j1 - j0 + 64) >> 6;

    float psum = 0.0f;
    for (int k = 0; k < nk; ++k) {
        const int j = j0 + lane + (k << 6);
        int ix, iy, iz; float e;
        const bool valid = (j <= j1) &&
            sample_vox(j, p0x, p0y, p0z, dx, dy, dz, L, s_tof, ix, iy, iz, e);
        if (mode != 2) {
            if (valid)
                psum += image[ix * 25600 + iy * 160 + iz] * (__expf(-e) * dl);
        }
        const unsigned key = valid
            ? (unsigned)((ix >> 3) * 400 + (iy >> 3) * 20 + (iz >> 3))
            : 0xFFFFFFFFu;
        const unsigned prev = __shfl_up(key, 1, 64);
        const bool chg = (lane == 0) || (prev != key);
        const unsigned long long cm = __ballot(chg);   // FULL-WAVE scope
        if (chg && valid) {
            const unsigned long long above = cm & ~((2ULL << lane) - 1ULL);
            const int nxt = above ? (__ffsll((unsigned long long)above) - 1) : 64;
            const int len = nxt - lane;                 // 1..64
            const unsigned word = ((unsigned)wave << 14)
                                | ((unsigned)j << 6) | (unsigned)(len - 1);
            if (mode == 1) {
                atomicAdd(&histcur[rep * NTILES + (int)key], 1);
            } else if (mode == 2) {
                const int slot = atomicAdd(&histcur[(int)key], 1);
                if (slot < ITEM_CAP) items[slot] = word;
            }
        }
    }
    if (mode != 2) {
        #pragma unroll
        for (int off = 32; off >= 1; off >>= 1) psum += __shfl_xor(psum, off, 64);
        if (lane == 0) p[wave] = psum;
    }
}

__global__ __launch_bounds__(256) void reduce_kernel(
    const int* __restrict__ hist8, int* __restrict__ tot)
{
    const int k = blockIdx.x * blockDim.x + threadIdx.x;
    if (k >= NTILES) return;
    int s = 0;
    #pragma unroll
    for (int r = 0; r < NREP; ++r) s += hist8[r * NTILES + k];
    tot[k] = s;
}

__global__ __launch_bounds__(1024) void scan_kernel(
    const int* __restrict__ tot, int* __restrict__ offs)
{
    __shared__ int part[1024];
    const int t = threadIdx.x;
    const int base = t * 8;
    int loc[8]; int s = 0;
    #pragma unroll
    for (int i = 0; i < 8; ++i) {
        const int h = (base + i < NTILES) ? tot[base + i] : 0;
        loc[i] = s; s += h;
    }
    part[t] = s;
    __syncthreads();
    for (int off = 1; off < 1024; off <<= 1) {
        int v = 0;
        if (t >= off) v = part[t - off];
        __syncthreads();
        part[t] += v;
        __syncthreads();
    }
    const int excl = (t > 0) ? part[t - 1] : 0;
    #pragma unroll
    for (int i = 0; i < 8; ++i)
        if (base + i < NTILES) offs[base + i] = excl + loc[i];
    if (t == 1023) offs[NTILES] = part[1023];
}

__global__ __launch_bounds__(256) void base_kernel(
    const int* __restrict__ offs, int* __restrict__ cursor)
{
    const int k = blockIdx.x * blockDim.x + threadIdx.x;
    if (k >= NTILES) return;
    cursor[k] = offs[k];
}

__global__ __launch_bounds__(256) void tileB_kernel(
    const float* __restrict__ image, const float* __restrict__ effmap,
    const LorT* __restrict__ lortab, const int* __restrict__ offs,
    const unsigned* __restrict__ items, const float* __restrict__ p,
    float* __restrict__ out)
{
    const int b = blockIdx.x;
    const int i0 = offs[b], i1 = min(offs[b + 1], ITEM_CAP);
    const int tx0 = (b / 400) << 3, ty0 = ((b / 20) % 20) << 3, tz0 = (b % 20) << 3;
    const int t = threadIdx.x;
    if (i0 >= i1) {
        for (int v = t; v < 512; v += 256) {
            const int lx = v >> 6, ly = (v >> 3) & 7, lz = v & 7;
            out[(size_t)(tx0 + lx) * 25600 + (ty0 + ly) * 160 + (tz0 + lz)] = 0.0f;
        }
        return;
    }
    __shared__ float acc[512];
    for (int v = t; v < 512; v += 256) acc[v] = 0.0f;
    __syncthreads();
    for (int idx = i0 + t; idx < i1; idx += 256) {
        const unsigned it = items[idx];
        const int lor = (int)(it >> 14);
        const int js  = (int)((it >> 6) & 255);
        const int len = (int)(it & 63) + 1;
        const float4 A = lortab[lor].a, B = lortab[lor].b;
        const float dl = B.w * (1.0f / 256.0f);
        const float s_tof = A.w * 0.15f;
        const float pv = p[lor];
        for (int m = 0; m < len; ++m) {
            int ix, iy, iz; float e;
            if (sample_vox(js + m, A.x, A.y, A.z, B.x, B.y, B.z, B.w, s_tof,
                           ix, iy, iz, e)) {
                const int lx = ix - tx0, ly = iy - ty0, lz = iz - tz0;
                if ((unsigned)lx < 8u && (unsigned)ly < 8u && (unsigned)lz < 8u)
                    atomicAdd(&acc[(lx << 6) | (ly << 3) | lz],
                              pv * (__expf(-e) * dl));
            }
        }
    }
    __syncthreads();
    for (int v = t; v < 512; v += 256) {
        const int lx = v >> 6, ly = (v >> 3) & 7, lz = v & 7;
        const size_t g = (size_t)(tx0 + lx) * 25600 + (ty0 + ly) * 160 + (tz0 + lz);
        out[g] = image[g] / (effmap[g] + 1e-8f) * acc[v];
    }
}

__global__ __launch_bounds__(256) void trace_direct_kernel(
    const float* __restrict__ image, const float* __restrict__ lors,
    float* __restrict__ bp, int n_lors)
{
#pragma clang fp contract(off)
    const int wave = (int)((blockIdx.x * blockDim.x + threadIdx.x) >> 6);
    const int lane = threadIdx.x & 63;
    if (wave >= n_lors) return;
    const float* l = lors + (size_t)wave * 7;
    const float p0x = l[0], p0y = l[1], p0z = l[2];
    const float dx = l[3] - p0x, dy = l[4] - p0y, dz = l[5] - p0z;
    const float tof = l[6];
    const float L  = sqrtf(dx * dx + dy * dy + dz * dz);
    const float dl = L * (1.0f / 256.0f);
    const float s_tof = tof * 0.15f;
    int j0, j1;
    lor_window(p0x, p0y, p0z, dx, dy, dz, L, s_tof, j0, j1);
    const int nk = (j1 - j0 + 64) >> 6;
    if (nk <= 0) return;
    int flat[4]; float w[4]; float psum = 0.0f;
    for (int k = 0; k < nk; ++k) {
        const int j = j0 + lane + (k << 6);
        int ix, iy, iz; float e; float wk = 0.0f; int fl = 0;
        if (j <= j1 &&
            sample_vox(j, p0x, p0y, p0z, dx, dy, dz, L, s_tof, ix, iy, iz, e)) {
            wk = __expf(-e) * dl;
            fl = ix * 25600 + iy * 160 + iz;
            psum += image[fl] * wk;
        }
        flat[k] = fl; w[k] = wk;
    }
    #pragma unroll
    for (int off = 32; off >= 1; off >>= 1) psum += __shfl_xor(psum, off, 64);
    for (int k = 0; k < nk; ++k)
        if (w[k] > 0.0f) atomicAdd(&bp[flat[k]], psum * w[k]);
}

__global__ __launch_bounds__(256) void finalize_kernel(
    const float4* __restrict__ image, const float4* __restrict__ effmap,
    float4* __restrict__ out, int n4)
{
    const int i = blockIdx.x * blockDim.x + threadIdx.x;
    if (i >= n4) return;
    const float4 im = image[i];
    const float4 ef = effmap[i];
    float4 b = out[i];
    b.x = im.x / (ef.x + 1e-8f) * b.x;
    b.y = im.y / (ef.y + 1e-8f) * b.y;
    b.z = im.z / (ef.z + 1e-8f) * b.z;
    b.w = im.w / (ef.w + 1e-8f) * b.w;
    out[i] = b;
}

extern "C" void kernel_launch(void* const* d_in, const int* in_sizes, int n_in,
                              void* d_out, int out_size, void* d_ws, size_t ws_size,
                              hipStream_t stream) {
    const float* image  = (const float*)d_in[0];
    const float* effmap = (const float*)d_in[1];
    const float* lors   = (const float*)d_in[2];
    float* out = (float*)d_out;
    const int n = in_sizes[2] / 7;

    char* ws = (char*)d_ws;
    const size_t scnt_off   = 0;                       // NREP*NTILES ints
    const size_t ovcnt_off  = scnt_off + (size_t)NREP * NTILES * 4;  // 256000
    const size_t ovg_off    = ovcnt_off + 256;
    const size_t ovv_off    = ovg_off + (size_t)OV_CAP * 4;
    const size_t bucket_off = ovv_off + (size_t)OV_CAP * 4;
    const size_t total_A    = bucket_off
                            + (size_t)NTILES * NREP * CAP_S * 4;     // ~132 MB
    // tier C layout (reuses front of ws)
    const size_t tot_off    = ovcnt_off;
    const size_t offs_off   = tot_off + 32768;
    const size_t cursor_off = offs_off + 32768;
    const size_t p_off      = cursor_off + 32768;
    const size_t lortab_off = p_off + (((size_t)n * 4 + 255) & ~(size_t)255);
    const size_t items_off2 = lortab_off + (size_t)n * sizeof(LorT);
    const size_t total_C    = items_off2 + (size_t)ITEM_CAP * 4;

    const int tileGrid = (NTILES + 255) / 256;

    if (ws_size >= total_A && n > 0 && n < (1 << 17)) {
        int*      scnt   = (int*)(ws + scnt_off);
        int*      ovcnt  = (int*)(ws + ovcnt_off);
        unsigned* ovg    = (unsigned*)(ws + ovg_off);
        float*    ovv    = (float*)(ws + ovv_off);
        unsigned* bucket = (unsigned*)(ws + bucket_off);

        // one memset covers scnt + ovcnt (contiguous, 256000 + 256 bytes)
        hipMemsetAsync(scnt, 0, (size_t)NREP * NTILES * 4 + 256, stream);

        const int blocksE = (n + 3) / 4;   // 4 waves/block, wave per LOR
        emit_bucket_kernel<<<blocksE, 256, 0, stream>>>(image, lors, scnt,
                                                        bucket, ovg, ovv,
                                                        ovcnt, n);
        tileB4_kernel<<<NTILES, 256, 0, stream>>>(image, effmap, scnt,
                                                  bucket, out);
        fold_overflow_kernel<<<64, 256, 0, stream>>>(image, effmap, ovg, ovv,
                                                     ovcnt, out);
    } else if (ws_size >= total_C && n > 0 && n < (1 << 17)) {
        int*      hist8  = (int*)(ws + scnt_off);
        int*      tot    = (int*)(ws + tot_off);
        int*      offs   = (int*)(ws + offs_off);
        int*      cursor = (int*)(ws + cursor_off);
        float*    p      = (float*)(ws + p_off);
        LorT*     lortab = (LorT*)(ws + lortab_off);
        unsigned* items  = (unsigned*)(ws + items_off2);

        hipMemsetAsync(hist8, 0, (size_t)NREP * NTILES * sizeof(int), stream);

        const int blocksE = (n + 3) / 4;
        emit_kernel<<<blocksE, 256, 0, stream>>>(image, lors, lortab, hist8,
                                                 items, p, n, 1);
        reduce_kernel<<<tileGrid, 256, 0, stream>>>(hist8, tot);
        scan_kernel<<<1, 1024, 0, stream>>>(tot, offs);
        base_kernel<<<tileGrid, 256, 0, stream>>>(offs, cursor);
        emit_kernel<<<blocksE, 256, 0, stream>>>(image, lors, lortab, cursor,
                                                 items, p, n, 2);
        tileB_kernel<<<NTILES, 256, 0, stream>>>(image, effmap, lortab, offs,
                                                 items, p, out);
    } else {
        hipMemsetAsync(out, 0, (size_t)NVOX * sizeof(float), stream);
        if (n > 0)
            trace_direct_kernel<<<(n + 3) / 4, 256, 0, stream>>>(image, lors, out, n);
        const int n4 = NVOX / 4;
        finalize_kernel<<<(n4 + 255) / 256, 256, 0, stream>>>(
            (const float4*)image, (const float4*)effmap, (float4*)out, n4);
    }
}

// Round 15
// 177.230 us; speedup vs baseline: 1.3852x; 1.0044x over previous
//
#include <hip/hip_runtime.h>
#include <hip/hip_fp16.h>
#include <math.h>

#define NSTEPS 256
#define GRIDN  160
#define NVOX   (160 * 160 * 160)
#define NTPA   20                  // tiles per axis (8^3-voxel tiles)
#define NTILES (NTPA * NTPA * NTPA)
#define NREP   8                   // bucket/hist replicas (~per-XCD)
#define CAP_S  512                 // sample slots per (tile, replica)
#define OV_CAP 65536               // overflow-entry capacity
#define ITEM_CAP (4 * 1024 * 1024)

#define INV_SIGMA 0.05233333f      // 2.355/45, fast path (weight only)

struct LorT { float4 a; float4 b; };   // a: p0.xyz, tof ; b: d.xyz, L

// ---- strict voxel path (contract OFF: bit-match f32 numpy floor decisions)
__device__ __forceinline__ bool sample_vox(
    int j, float p0x, float p0y, float p0z,
    float dx, float dy, float dz, float L, float s_tof,
    int& ix, int& iy, int& iz, float& e)
{
#pragma clang fp contract(off)
    const float t = (j + 0.5f) * (1.0f / 256.0f);
    const float px = p0x + t * dx;
    const float py = p0y + t * dy;
    const float pz = p0z + t * dz;
    const float fx = floorf((px + 160.0f) * 0.5f);
    const float fy = floorf((py + 160.0f) * 0.5f);
    const float fz = floorf((pz + 160.0f) * 0.5f);
    const bool inb = (fx >= 0.0f) & (fx < 160.0f) &
                     (fy >= 0.0f) & (fy < 160.0f) &
                     (fz >= 0.0f) & (fz < 160.0f);
    const float s = (t - 0.5f) * L;
    const float u = (s - s_tof) * INV_SIGMA;   // fast: mul, not strict div
    e = 0.5f * (u * u);
    if (inb & (e < 10.0f)) {
        ix = (int)fx; iy = (int)fy; iz = (int)fz;
        return true;
    }
    return false;
}

__device__ __forceinline__ void lor_window(
    float p0x, float p0y, float p0z, float dx, float dy, float dz,
    float L, float s_tof, int& j0, int& j1)
{
#pragma clang fp contract(off)
    const float SIGMA = (float)(45.0 / 2.355);
    const float CUTS  = 4.4721360f * SIGMA;      // e<10 support
    const float invL = 1.0f / L;
    float t0 = 0.5f + (s_tof - CUTS) * invL;
    float t1 = 0.5f + (s_tof + CUTS) * invL;
    if (t0 > t1) { const float tmp = t0; t0 = t1; t1 = tmp; }
    const float pc[3] = {p0x, p0y, p0z};
    const float dc[3] = {dx, dy, dz};
    #pragma unroll
    for (int a = 0; a < 3; ++a) {
        if (dc[a] != 0.0f) {
            const float inv = 1.0f / dc[a];
            const float ta = (-160.0f - pc[a]) * inv;
            const float tb = ( 160.0f - pc[a]) * inv;
            t0 = fmaxf(t0, fminf(ta, tb));
            t1 = fminf(t1, fmaxf(ta, tb));
        } else if (pc[a] < -160.0f || pc[a] >= 160.0f) t1 = -1.0f;
    }
    t0 = fmaxf(t0, 0.0f);
    t1 = fminf(t1, 1.0f);
    j0 = (int)floorf(t0 * 256.0f - 0.5f) - 2;
    j1 = (int)ceilf (t1 * 256.0f - 0.5f) + 2;
    if (!(t0 <= t1)) { j0 = 0; j1 = -1; }
    j0 = max(j0, 0);
    j1 = min(j1, NSTEPS - 1);
}

// ---- tier A emission (R14 lineage, passed): one wave per LOR, two
//      register-resident passes. Pass 1: trace + forward psum (wave-reduce).
//      Pass 2: run-length segments; leader reserves len slots with ONE
//      atomicAdd on scnt[rep][key]; base shfl-broadcast; each valid lane
//      stores its FINAL bp entry (lidx<<16 | fp16(pv*w)) contiguously.
//      Overflow (slot >= CAP_S) -> (g, v) list, applied by the owning
//      tile's block in tileB4 (R15: fold dispatch removed).
//      R15 micro-opt: wave-uniform skip of empty k-slots in pass 2
//      (j0/j1 are wave-uniform; typical window spans 2-3 of 4 slots).
//      Ballots at FULL-WAVE scope (R9 lesson).
__global__ __launch_bounds__(256) void emit_bucket_kernel(
    const float* __restrict__ image, const float* __restrict__ lors,
    int* __restrict__ scnt, unsigned* __restrict__ bucket,
    unsigned* __restrict__ ovg, float* __restrict__ ovv,
    int* __restrict__ ovcnt, int n)
{
#pragma clang fp contract(off)
    const int wave = (int)((blockIdx.x * blockDim.x + threadIdx.x) >> 6);
    const int lane = threadIdx.x & 63;
    if (wave >= n) return;
    const int rep = (int)(blockIdx.x & (NREP - 1));

    const float* l = lors + (size_t)wave * 7;
    const float p0x = l[0], p0y = l[1], p0z = l[2];
    const float dx = l[3] - p0x, dy = l[4] - p0y, dz = l[5] - p0z;
    const float tof = l[6];
    const float L  = sqrtf(dx * dx + dy * dy + dz * dz);
    const float s_tof = tof * 0.15f;
    const float dl = L * (1.0f / 256.0f);
    int j0, j1;
    lor_window(p0x, p0y, p0z, dx, dy, dz, L, s_tof, j0, j1);

    // pass 1: trace into registers (full unroll -> static indices, rule #20)
    float    wk[4];
    unsigned kk[4];                      // (key<<9)|lidx, 0xFFFFFFFF invalid
    float psum = 0.0f;
    #pragma unroll
    for (int k = 0; k < 4; ++k) {
        wk[k] = 0.0f; kk[k] = 0xFFFFFFFFu;
        const int j = j0 + lane + (k << 6);
        if (j <= j1) {
            int ix, iy, iz; float e;
            if (sample_vox(j, p0x, p0y, p0z, dx, dy, dz, L, s_tof,
                           ix, iy, iz, e)) {
                const float w = __expf(-e) * dl;
                wk[k] = w;
                kk[k] = (((unsigned)((ix >> 3) * 400 + (iy >> 3) * 20
                                     + (iz >> 3))) << 9)
                      | (unsigned)(((ix & 7) << 6) | ((iy & 7) << 3) | (iz & 7));
                psum += image[ix * 25600 + iy * 160 + iz] * w;
            }
        }
    }
    #pragma unroll
    for (int off = 32; off >= 1; off >>= 1) psum += __shfl_xor(psum, off, 64);
    // psum == pv on all lanes now

    // pass 2: segment-reserved bucket writes
    #pragma unroll
    for (int k = 0; k < 4; ++k) {
        if (j0 + (k << 6) > j1) continue;          // wave-uniform empty slot
        const bool valid = (kk[k] != 0xFFFFFFFFu);
        const unsigned key = kk[k] >> 9;           // sentinel -> 0x7FFFFF
        const unsigned prev = __shfl_up(key, 1, 64);
        const bool chg = (lane == 0) || (prev != key);
        const unsigned long long cm = __ballot(chg);            // FULL WAVE
        const unsigned long long below = cm & ((2ULL << lane) - 1ULL);
        const int leader = 63 - __clzll((long long)below);      // below != 0
        const unsigned long long above = cm & ~((2ULL << lane) - 1ULL);
        const int nxt = above ? (__ffsll((long long)above) - 1) : 64;
        int tr = 0;
        if (chg && valid)
            tr = atomicAdd(&scnt[rep * NTILES + (int)key], nxt - lane);
        tr = __shfl(tr, leader, 64);
        if (valid) {
            const int slot = tr + (lane - leader);
            const float v = psum * wk[k];
            if (slot < CAP_S) {
                const unsigned entry = ((kk[k] & 511u) << 16)
                    | (unsigned)__half_as_ushort(__float2half(v));
                bucket[((size_t)key * NREP + rep) * CAP_S + slot] = entry;
            } else {                       // rare overflow -> (g, v) list
                const int ky = (int)key;
                const int tx = ky / 400, ty = (ky / 20) % 20, tz = ky % 20;
                const int lidx = (int)(kk[k] & 511u);
                const unsigned g =
                    (unsigned)((tx * 8 + (lidx >> 6)) * 25600
                             + (ty * 8 + ((lidx >> 3) & 7)) * 160
                             + (tz * 8 + (lidx & 7)));
                const int oi = atomicAdd(ovcnt, 1);
                if (oi < OV_CAP) { ovg[oi] = g; ovv[oi] = v; }
            }
        }
    }
}

// ---- tier A pass B (R14 lineage): thread-per-sample over the tile's bucket
//      ranges. One coalesced 4B load -> unpack -> LDS atomic. R15 change:
//      each block folds ITS OWN tile's overflow entries into acc before the
//      epilogue (fold dispatch removed; oc==0 in practice so the scan is one
//      uniform load). Empty tiles write zeros (no out memset); epilogue is
//      a pure write.
__global__ __launch_bounds__(256) void tileB4_kernel(
    const float* __restrict__ image, const float* __restrict__ effmap,
    const int* __restrict__ scnt, const unsigned* __restrict__ bucket,
    const unsigned* __restrict__ ovg, const float* __restrict__ ovv,
    const int* __restrict__ ovcnt, float* __restrict__ out)
{
    const int b = blockIdx.x;
    const int t = threadIdx.x;
    const int tx0 = (b / 400) << 3, ty0 = ((b / 20) % 20) << 3, tz0 = (b % 20) << 3;
    int pre[NREP]; int tot = 0;
    #pragma unroll
    for (int r = 0; r < NREP; ++r) {
        int c = scnt[r * NTILES + b];
        c = min(c, CAP_S);
        pre[r] = tot; tot += c;
    }
    if (tot == 0) {          // uncovered tile: bp = 0 -> out = 0
                             // (overflow needs scnt >= CAP_S, so tot > 0)
        for (int v = t; v < 512; v += 256) {
            const int lx = v >> 6, ly = (v >> 3) & 7, lz = v & 7;
            out[(size_t)(tx0 + lx) * 25600 + (ty0 + ly) * 160 + (tz0 + lz)] = 0.0f;
        }
        return;
    }
    __shared__ float acc[512];
    for (int v = t; v < 512; v += 256) acc[v] = 0.0f;
    __syncthreads();
    for (int idx = t; idx < tot; idx += 256) {
        int r = 0, base = 0;
        #pragma unroll
        for (int rr = 1; rr < NREP; ++rr) {
            const bool g = (idx >= pre[rr]);
            r    = g ? rr      : r;
            base = g ? pre[rr] : base;
        }
        const unsigned e = bucket[((size_t)b * NREP + r) * CAP_S + (idx - base)];
        atomicAdd(&acc[(e >> 16) & 511u],
                  __half2float(__ushort_as_half((unsigned short)(e & 0xFFFFu))));
    }
    // fold this tile's overflow entries (oc == 0 in practice)
    const int oc = min(*ovcnt, OV_CAP);
    for (int i = t; i < oc; i += 256) {
        const unsigned g = ovg[i];
        const int gx = (int)(g / 25600u);
        const int rm = (int)(g % 25600u);
        const int gy = rm / 160, gz = rm % 160;
        if ((gx >> 3) == (tx0 >> 3) && (gy >> 3) == (ty0 >> 3)
            && (gz >> 3) == (tz0 >> 3))
            atomicAdd(&acc[((gx & 7) << 6) | ((gy & 7) << 3) | (gz & 7)],
                      ovv[i]);
    }
    __syncthreads();
    for (int v = t; v < 512; v += 256) {
        const int lx = v >> 6, ly = (v >> 3) & 7, lz = v & 7;
        const size_t g = (size_t)(tx0 + lx) * 25600 + (ty0 + ly) * 160 + (tz0 + lz);
        out[g] = image[g] / (effmap[g] + 1e-8f) * acc[v];
    }
}

// ======== tier C fallback (flat items, two-phase; verified lineage) ========
__global__ __launch_bounds__(256) void emit_kernel(
    const float* __restrict__ image,
    const float* __restrict__ lors, LorT* __restrict__ lortab,
    int* __restrict__ histcur, unsigned* __restrict__ items,
    float* __restrict__ p,
    int n, int mode)
{
#pragma clang fp contract(off)
    const int wave = (int)((blockIdx.x * blockDim.x + threadIdx.x) >> 6);
    const int lane = threadIdx.x & 63;
    if (wave >= n) return;
    const int rep = (int)(blockIdx.x & (NREP - 1));

    float p0x, p0y, p0z, tof, dx, dy, dz, L;
    if (mode != 2) {
        const float* l = lors + (size_t)wave * 7;
        p0x = l[0]; p0y = l[1]; p0z = l[2];
        dx = l[3] - p0x; dy = l[4] - p0y; dz = l[5] - p0z; tof = l[6];
        L = sqrtf(dx * dx + dy * dy + dz * dz);
        if (lane == 0) {
            lortab[wave].a = make_float4(p0x, p0y, p0z, tof);
            lortab[wave].b = make_float4(dx, dy, dz, L);
        }
    } else {
        const float4 A = lortab[wave].a, B = lortab[wave].b;
        p0x = A.x; p0y = A.y; p0z = A.z; tof = A.w;
        dx  = B.x; dy  = B.y; dz  = B.z; L   = B.w;
    }
    const float s_tof = tof * 0.15f;
    const float dl = L * (1.0f / 256.0f);
    int j0, j1;
    lor_window(p0x, p0y, p0z, dx, dy, dz, L, s_tof, j0, j1);
    const int nk = (j1 - j0 + 64) >> 6;

    float psum = 0.0f;
    for (int k = 0; k < nk; ++k) {
        const int j = j0 + lane + (k << 6);
        int ix, iy, iz; float e;
        const bool valid = (j <= j1) &&
            sample_vox(j, p0x, p0y, p0z, dx, dy, dz, L, s_tof, ix, iy, iz, e);
        if (mode != 2) {
            if (valid)
                psum += image[ix * 25600 + iy * 160 + iz] * (__expf(-e) * dl);
        }
        const unsigned key = valid
            ? (unsigned)((ix >> 3) * 400 + (iy >> 3) * 20 + (iz >> 3))
            : 0xFFFFFFFFu;
        const unsigned prev = __shfl_up(key, 1, 64);
        const bool chg = (lane == 0) || (prev != key);
        const unsigned long long cm = __ballot(chg);   // FULL-WAVE scope
        if (chg && valid) {
            const unsigned long long above = cm & ~((2ULL << lane) - 1ULL);
            const int nxt = above ? (__ffsll((unsigned long long)above) - 1) : 64;
            const int len = nxt - lane;                 // 1..64
            const unsigned word = ((unsigned)wave << 14)
                                | ((unsigned)j << 6) | (unsigned)(len - 1);
            if (mode == 1) {
                atomicAdd(&histcur[rep * NTILES + (int)key], 1);
            } else if (mode == 2) {
                const int slot = atomicAdd(&histcur[(int)key], 1);
                if (slot < ITEM_CAP) items[slot] = word;
            }
        }
    }
    if (mode != 2) {
        #pragma unroll
        for (int off = 32; off >= 1; off >>= 1) psum += __shfl_xor(psum, off, 64);
        if (lane == 0) p[wave] = psum;
    }
}

__global__ __launch_bounds__(256) void reduce_kernel(
    const int* __restrict__ hist8, int* __restrict__ tot)
{
    const int k = blockIdx.x * blockDim.x + threadIdx.x;
    if (k >= NTILES) return;
    int s = 0;
    #pragma unroll
    for (int r = 0; r < NREP; ++r) s += hist8[r * NTILES + k];
    tot[k] = s;
}

__global__ __launch_bounds__(1024) void scan_kernel(
    const int* __restrict__ tot, int* __restrict__ offs)
{
    __shared__ int part[1024];
    const int t = threadIdx.x;
    const int base = t * 8;
    int loc[8]; int s = 0;
    #pragma unroll
    for (int i = 0; i < 8; ++i) {
        const int h = (base + i < NTILES) ? tot[base + i] : 0;
        loc[i] = s; s += h;
    }
    part[t] = s;
    __syncthreads();
    for (int off = 1; off < 1024; off <<= 1) {
        int v = 0;
        if (t >= off) v = part[t - off];
        __syncthreads();
        part[t] += v;
        __syncthreads();
    }
    const int excl = (t > 0) ? part[t - 1] : 0;
    #pragma unroll
    for (int i = 0; i < 8; ++i)
        if (base + i < NTILES) offs[base + i] = excl + loc[i];
    if (t == 1023) offs[NTILES] = part[1023];
}

__global__ __launch_bounds__(256) void base_kernel(
    const int* __restrict__ offs, int* __restrict__ cursor)
{
    const int k = blockIdx.x * blockDim.x + threadIdx.x;
    if (k >= NTILES) return;
    cursor[k] = offs[k];
}

__global__ __launch_bounds__(256) void tileB_kernel(
    const float* __restrict__ image, const float* __restrict__ effmap,
    const LorT* __restrict__ lortab, const int* __restrict__ offs,
    const unsigned* __restrict__ items, const float* __restrict__ p,
    float* __restrict__ out)
{
    const int b = blockIdx.x;
    const int i0 = offs[b], i1 = min(offs[b + 1], ITEM_CAP);
    const int tx0 = (b / 400) << 3, ty0 = ((b / 20) % 20) << 3, tz0 = (b % 20) << 3;
    const int t = threadIdx.x;
    if (i0 >= i1) {
        for (int v = t; v < 512; v += 256) {
            const int lx = v >> 6, ly = (v >> 3) & 7, lz = v & 7;
            out[(size_t)(tx0 + lx) * 25600 + (ty0 + ly) * 160 + (tz0 + lz)] = 0.0f;
        }
        return;
    }
    __shared__ float acc[512];
    for (int v = t; v < 512; v += 256) acc[v] = 0.0f;
    __syncthreads();
    for (int idx = i0 + t; idx < i1; idx += 256) {
        const unsigned it = items[idx];
        const int lor = (int)(it >> 14);
        const int js  = (int)((it >> 6) & 255);
        const int len = (int)(it & 63) + 1;
        const float4 A = lortab[lor].a, B = lortab[lor].b;
        const float dl = B.w * (1.0f / 256.0f);
        const float s_tof = A.w * 0.15f;
        const float pv = p[lor];
        for (int m = 0; m < len; ++m) {
            int ix, iy, iz; float e;
            if (sample_vox(js + m, A.x, A.y, A.z, B.x, B.y, B.z, B.w, s_tof,
                           ix, iy, iz, e)) {
                const int lx = ix - tx0, ly = iy - ty0, lz = iz - tz0;
                if ((unsigned)lx < 8u && (unsigned)ly < 8u && (unsigned)lz < 8u)
                    atomicAdd(&acc[(lx << 6) | (ly << 3) | lz],
                              pv * (__expf(-e) * dl));
            }
        }
    }
    __syncthreads();
    for (int v = t; v < 512; v += 256) {
        const int lx = v >> 6, ly = (v >> 3) & 7, lz = v & 7;
        const size_t g = (size_t)(tx0 + lx) * 25600 + (ty0 + ly) * 160 + (tz0 + lz);
        out[g] = image[g] / (effmap[g] + 1e-8f) * acc[v];
    }
}

__global__ __launch_bounds__(256) void trace_direct_kernel(
    const float* __restrict__ image, const float* __restrict__ lors,
    float* __restrict__ bp, int n_lors)
{
#pragma clang fp contract(off)
    const int wave = (int)((blockIdx.x * blockDim.x + threadIdx.x) >> 6);
    const int lane = threadIdx.x & 63;
    if (wave >= n_lors) return;
    const float* l = lors + (size_t)wave * 7;
    const float p0x = l[0], p0y = l[1], p0z = l[2];
    const float dx = l[3] - p0x, dy = l[4] - p0y, dz = l[5] - p0z;
    const float tof = l[6];
    const float L  = sqrtf(dx * dx + dy * dy + dz * dz);
    const float dl = L * (1.0f / 256.0f);
    const float s_tof = tof * 0.15f;
    int j0, j1;
    lor_window(p0x, p0y, p0z, dx, dy, dz, L, s_tof, j0, j1);
    const int nk = (j1 - j0 + 64) >> 6;
    if (nk <= 0) return;
    int flat[4]; float w[4]; float psum = 0.0f;
    for (int k = 0; k < nk; ++k) {
        const int j = j0 + lane + (k << 6);
        int ix, iy, iz; float e; float wk = 0.0f; int fl = 0;
        if (j <= j1 &&
            sample_vox(j, p0x, p0y, p0z, dx, dy, dz, L, s_tof, ix, iy, iz, e)) {
            wk = __expf(-e) * dl;
            fl = ix * 25600 + iy * 160 + iz;
            psum += image[fl] * wk;
        }
        flat[k] = fl; w[k] = wk;
    }
    #pragma unroll
    for (int off = 32; off >= 1; off >>= 1) psum += __shfl_xor(psum, off, 64);
    for (int k = 0; k < nk; ++k)
        if (w[k] > 0.0f) atomicAdd(&bp[flat[k]], psum * w[k]);
}

__global__ __launch_bounds__(256) void finalize_kernel(
    const float4* __restrict__ image, const float4* __restrict__ effmap,
    float4* __restrict__ out, int n4)
{
    const int i = blockIdx.x * blockDim.x + threadIdx.x;
    if (i >= n4) return;
    const float4 im = image[i];
    const float4 ef = effmap[i];
    float4 b = out[i];
    b.x = im.x / (ef.x + 1e-8f) * b.x;
    b.y = im.y / (ef.y + 1e-8f) * b.y;
    b.z = im.z / (ef.z + 1e-8f) * b.z;
    b.w = im.w / (ef.w + 1e-8f) * b.w;
    out[i] = b;
}

extern "C" void kernel_launch(void* const* d_in, const int* in_sizes, int n_in,
                              void* d_out, int out_size, void* d_ws, size_t ws_size,
                              hipStream_t stream) {
    const float* image  = (const float*)d_in[0];
    const float* effmap = (const float*)d_in[1];
    const float* lors   = (const float*)d_in[2];
    float* out = (float*)d_out;
    const int n = in_sizes[2] / 7;

    char* ws = (char*)d_ws;
    const size_t scnt_off   = 0;                       // NREP*NTILES ints
    const size_t ovcnt_off  = scnt_off + (size_t)NREP * NTILES * 4;  // 256000
    const size_t ovg_off    = ovcnt_off + 256;
    const size_t ovv_off    = ovg_off + (size_t)OV_CAP * 4;
    const size_t bucket_off = ovv_off + (size_t)OV_CAP * 4;
    const size_t total_A    = bucket_off
                            + (size_t)NTILES * NREP * CAP_S * 4;     // ~132 MB
    // tier C layout (reuses front of ws)
    const size_t tot_off    = ovcnt_off;
    const size_t offs_off   = tot_off + 32768;
    const size_t cursor_off = offs_off + 32768;
    const size_t p_off      = cursor_off + 32768;
    const size_t lortab_off = p_off + (((size_t)n * 4 + 255) & ~(size_t)255);
    const size_t items_off2 = lortab_off + (size_t)n * sizeof(LorT);
    const size_t total_C    = items_off2 + (size_t)ITEM_CAP * 4;

    const int tileGrid = (NTILES + 255) / 256;

    if (ws_size >= total_A && n > 0 && n < (1 << 17)) {
        int*      scnt   = (int*)(ws + scnt_off);
        int*      ovcnt  = (int*)(ws + ovcnt_off);
        unsigned* ovg    = (unsigned*)(ws + ovg_off);
        float*    ovv    = (float*)(ws + ovv_off);
        unsigned* bucket = (unsigned*)(ws + bucket_off);

        // one memset covers scnt + ovcnt (contiguous, 256000 + 256 bytes)
        hipMemsetAsync(scnt, 0, (size_t)NREP * NTILES * 4 + 256, stream);

        const int blocksE = (n + 3) / 4;   // 4 waves/block, wave per LOR
        emit_bucket_kernel<<<blocksE, 256, 0, stream>>>(image, lors, scnt,
                                                        bucket, ovg, ovv,
                                                        ovcnt, n);
        tileB4_kernel<<<NTILES, 256, 0, stream>>>(image, effmap, scnt, bucket,
                                                  ovg, ovv, ovcnt, out);
    } else if (ws_size >= total_C && n > 0 && n < (1 << 17)) {
        int*      hist8  = (int*)(ws + scnt_off);
        int*      tot    = (int*)(ws + tot_off);
        int*      offs   = (int*)(ws + offs_off);
        int*      cursor = (int*)(ws + cursor_off);
        float*    p      = (float*)(ws + p_off);
        LorT*     lortab = (LorT*)(ws + lortab_off);
        unsigned* items  = (unsigned*)(ws + items_off2);

        hipMemsetAsync(hist8, 0, (size_t)NREP * NTILES * sizeof(int), stream);

        const int blocksE = (n + 3) / 4;
        emit_kernel<<<blocksE, 256, 0, stream>>>(image, lors, lortab, hist8,
                                                 items, p, n, 1);
        reduce_kernel<<<tileGrid, 256, 0, stream>>>(hist8, tot);
        scan_kernel<<<1, 1024, 0, stream>>>(tot, offs);
        base_kernel<<<tileGrid, 256, 0, stream>>>(offs, cursor);
        emit_kernel<<<blocksE, 256, 0, stream>>>(image, lors, lortab, cursor,
                                                 items, p, n, 2);
        tileB_kernel<<<NTILES, 256, 0, stream>>>(image, effmap, lortab, offs,
                                                 items, p, out);
    } else {
        hipMemsetAsync(out, 0, (size_t)NVOX * sizeof(float), stream);
        if (n > 0)
            trace_direct_kernel<<<(n + 3) / 4, 256, 0, stream>>>(image, lors, out, n);
        const int n4 = NVOX / 4;
        finalize_kernel<<<(n4 + 255) / 256, 256, 0, stream>>>(
            (const float4*)image, (const float4*)effmap, (float4*)out, n4);
    }
}